// Round 1
// baseline (125.391 us; speedup 1.0000x reference)
//
#include <hip/hip_runtime.h>

#define BT 262144
#define TILE 128
#define BLOCK 512
#define WAVES 8

typedef __attribute__((ext_vector_type(8))) short short8;
typedef __attribute__((ext_vector_type(4))) float f32x4;

__device__ __forceinline__ unsigned short f2bf(float f) {
  union { float f; unsigned u; } v; v.f = f;
  unsigned r = v.u + 0x7FFFu + ((v.u >> 16) & 1u);
  return (unsigned short)(r >> 16);
}

__device__ __forceinline__ float sigm(float x) { return 1.0f / (1.0f + __expf(-x)); }
__device__ __forceinline__ float tanh_(float x) {
  float e = __expf(-2.0f * x);
  return (1.0f - e) / (1.0f + e);
}

// Prep: W_eff = W_ih @ W_in, b_eff = b_ih + b_hh + W_ih @ b_in.
// Pack W_eff^T, W_hh^T, W_out^T as bf16 MFMA B-fragments:
//   frag id layout: (((ks*NT + nt)*64 + lane)*8 + j), value = W[n][k],
//   n = nt*16 + (lane&15), k = ks*32 + (lane>>4)*8 + j.
__global__ void prep_kernel(const float* __restrict__ W_in, const float* __restrict__ b_in,
                            const float* __restrict__ W_ih, const float* __restrict__ W_hh,
                            const float* __restrict__ b_ih, const float* __restrict__ b_hh,
                            const float* __restrict__ W_out,
                            unsigned short* __restrict__ wsW, float* __restrict__ ws_beff) {
  int id = blockIdx.x * blockDim.x + threadIdx.x;
  if (id < 16384) {                       // W_eff fragments (16 ntiles, 2 ksteps)
    int j = id & 7, l = (id >> 3) & 63, nt = (id >> 9) & 15, ks = id >> 13;
    int n = nt * 16 + (l & 15);
    int k = ks * 32 + (l >> 4) * 8 + j;
    float s = 0.f;
    #pragma unroll 8
    for (int h = 0; h < 64; ++h) s = fmaf(W_ih[n * 64 + h], W_in[h * 64 + k], s);
    wsW[id] = f2bf(s);
  } else if (id < 32768) {                // W_hh fragments
    int e = id - 16384;
    int j = e & 7, l = (e >> 3) & 63, nt = (e >> 9) & 15, ks = e >> 13;
    int n = nt * 16 + (l & 15);
    int k = ks * 32 + (l >> 4) * 8 + j;
    wsW[id] = f2bf(W_hh[n * 64 + k]);
  } else if (id < 33792) {                // W_out fragments (1 ntile, 2 ksteps)
    int e = id - 32768;
    int j = e & 7, l = (e >> 3) & 63, ks = e >> 9;
    int n = l & 15;
    int k = ks * 32 + (l >> 4) * 8 + j;
    wsW[id] = f2bf(W_out[n * 64 + k]);
  } else if (id < 34048) {                // b_eff
    int n = id - 33792;
    float s = b_ih[n] + b_hh[n];
    #pragma unroll 8
    for (int h = 0; h < 64; ++h) s = fmaf(W_ih[n * 64 + h], b_in[h], s);
    ws_beff[n] = s;
  }
}

__device__ __forceinline__ short8 load_pack8(const float* p) {
  float4 lo = *(const float4*)p;
  float4 hi = *(const float4*)(p + 4);
  short8 r;
  r[0] = (short)f2bf(lo.x); r[1] = (short)f2bf(lo.y);
  r[2] = (short)f2bf(lo.z); r[3] = (short)f2bf(lo.w);
  r[4] = (short)f2bf(hi.x); r[5] = (short)f2bf(hi.y);
  r[6] = (short)f2bf(hi.z); r[7] = (short)f2bf(hi.w);
  return r;
}

__global__ __launch_bounds__(BLOCK, 1) void lstm_main(
    const float* __restrict__ obs, const float* __restrict__ h0,
    const float* __restrict__ c0, const float* __restrict__ b_out,
    const unsigned short* __restrict__ wsW, const float* __restrict__ ws_beff,
    float* __restrict__ out) {
  // LDS: weight fragments (67584 B) + b_eff (1 KB) + per-wave h_new frag buf (16 KB)
  __shared__ __attribute__((aligned(16))) unsigned short wfrag[33792];
  __shared__ float beff_s[256];
  __shared__ __attribute__((aligned(16))) unsigned short hfrag[WAVES][2][64][8];

  const int tid = threadIdx.x;
  // stage packed weights ws -> LDS (uint4 = 8 bf16): 4224 chunks
  for (int i = tid; i < 4224; i += BLOCK)
    ((uint4*)wfrag)[i] = ((const uint4*)wsW)[i];
  if (tid < 256) beff_s[tid] = ws_beff[tid];
  __syncthreads();

  const int wv = tid >> 6;
  const int lane = tid & 63;
  const int l16 = lane & 15;
  const int q = lane >> 4;                 // 0..3
  const size_t rowbase = (size_t)blockIdx.x * TILE + (size_t)wv * 16;

  // A-fragments: lane holds row (l16), k = ks*32 + q*8 + j  (8 consecutive f32)
  short8 aObs[2], aH[2];
  #pragma unroll
  for (int ks = 0; ks < 2; ++ks) {
    const float* po = obs + (rowbase + l16) * 64 + ks * 32 + q * 8;
    aObs[ks] = load_pack8(po);
    const float* ph = h0 + (rowbase + l16) * 64 + ks * 32 + q * 8;
    aH[ks] = load_pack8(ph);
  }

  // gates = obs@W_eff^T + h@W_hh^T + b_eff ; acc[t] covers cols t*16..t*16+15
  f32x4 acc[16];
  #pragma unroll
  for (int t = 0; t < 16; ++t) {
    float b = beff_s[t * 16 + l16];
    acc[t] = (f32x4){b, b, b, b};
  }
  const short8* wE = (const short8*)wfrag;            // [2][16][64]
  const short8* wH = (const short8*)(wfrag + 16384);  // [2][16][64]
  const short8* wO = (const short8*)(wfrag + 32768);  // [2][64]
  #pragma unroll
  for (int ks = 0; ks < 2; ++ks) {
    #pragma unroll
    for (int t = 0; t < 16; ++t) {
      acc[t] = __builtin_amdgcn_mfma_f32_16x16x32_bf16(aObs[ks], wE[(ks * 16 + t) * 64 + lane], acc[t], 0, 0, 0);
      acc[t] = __builtin_amdgcn_mfma_f32_16x16x32_bf16(aH[ks],  wH[(ks * 16 + t) * 64 + lane], acc[t], 0, 0, 0);
    }
  }

  // elementwise LSTM cell; D layout: lane holds row 4*q+r, col t*16+l16
  float* out_act = out;
  float* out_h = out + (size_t)BT * 16;
  float* out_c = out + (size_t)BT * 16 + (size_t)BT * 64;

  #pragma unroll
  for (int t = 0; t < 4; ++t) {
    #pragma unroll
    for (int r = 0; r < 4; ++r) {
      float iv = sigm(acc[t][r]);
      float fv = sigm(acc[t + 4][r]);
      float gv = tanh_(acc[t + 8][r]);
      float ov = sigm(acc[t + 12][r]);
      size_t m = rowbase + (size_t)(4 * q + r);
      int n = t * 16 + l16;
      float cold = c0[m * 64 + n];
      float cnew = fmaf(fv, cold, iv * gv);
      float hnew = ov * tanh_(cnew);
      out_c[m * 64 + n] = cnew;
      out_h[m * 64 + n] = hnew;
      // scatter h_new into A-fragment layout for the W_out MFMA
      int ks = n >> 5;
      int lp = (4 * q + r) + 16 * ((n & 31) >> 3);
      int j = n & 7;
      hfrag[wv][ks][lp][j] = f2bf(hnew);
    }
  }
  __syncthreads();

  // action = tanh(h_new @ W_out^T + b_out); ACTION range [-1,1] => identity map
  float bo = b_out[l16];
  f32x4 accA = (f32x4){bo, bo, bo, bo};
  short8 a0 = *(const short8*)&hfrag[wv][0][lane][0];
  short8 a1 = *(const short8*)&hfrag[wv][1][lane][0];
  accA = __builtin_amdgcn_mfma_f32_16x16x32_bf16(a0, wO[lane], accA, 0, 0, 0);
  accA = __builtin_amdgcn_mfma_f32_16x16x32_bf16(a1, wO[64 + lane], accA, 0, 0, 0);
  #pragma unroll
  for (int r = 0; r < 4; ++r) {
    size_t m = rowbase + (size_t)(4 * q + r);
    out_act[m * 16 + l16] = tanh_(accA[r]);
  }
}

extern "C" void kernel_launch(void* const* d_in, const int* in_sizes, int n_in,
                              void* d_out, int out_size, void* d_ws, size_t ws_size,
                              hipStream_t stream) {
  const float* obs  = (const float*)d_in[0];
  const float* h0   = (const float*)d_in[1];
  const float* c0   = (const float*)d_in[2];
  const float* W_in = (const float*)d_in[3];
  const float* b_in = (const float*)d_in[4];
  const float* W_ih = (const float*)d_in[5];
  const float* W_hh = (const float*)d_in[6];
  const float* b_ih = (const float*)d_in[7];
  const float* b_hh = (const float*)d_in[8];
  const float* W_out = (const float*)d_in[9];
  const float* b_out = (const float*)d_in[10];

  unsigned short* wsW = (unsigned short*)d_ws;
  float* ws_beff = (float*)((char*)d_ws + 67584);

  prep_kernel<<<133, 256, 0, stream>>>(W_in, b_in, W_ih, W_hh, b_ih, b_hh, W_out, wsW, ws_beff);
  lstm_main<<<BT / TILE, BLOCK, 0, stream>>>(obs, h0, c0, b_out, wsW, ws_beff, (float*)d_out);
}

// Round 2
// 106.555 us; speedup vs baseline: 1.1768x; 1.1768x over previous
//
#include <hip/hip_runtime.h>
#include <hip/hip_bf16.h>

#define BT 262144
#define TILE 128
#define BLOCK 512
#define WAVES 8

typedef __attribute__((ext_vector_type(8))) short short8;
typedef __attribute__((ext_vector_type(4))) float f32x4;

__device__ __forceinline__ unsigned short f2bf(float f) {
  __hip_bfloat16 b = __float2bfloat16(f);
  union { __hip_bfloat16 b; unsigned short u; } v;
  v.b = b;
  return v.u;
}

__device__ __forceinline__ float sigm(float x) { return 1.0f / (1.0f + __expf(-x)); }
__device__ __forceinline__ float tanh_(float x) {
  float e = __expf(-2.0f * x);
  return (1.0f - e) / (1.0f + e);
}

// Prep: W_eff = W_ih @ W_in, b_eff = b_ih + b_hh + W_ih @ b_in.
// Pack W_eff^T, W_hh^T, W_out^T as bf16 MFMA B-fragments:
//   frag id layout: (((ks*NT + nt)*64 + lane)*8 + j), value = W[n][k],
//   n = nt*16 + (lane&15), k = ks*32 + (lane>>4)*8 + j.
__global__ void prep_kernel(const float* __restrict__ W_in, const float* __restrict__ b_in,
                            const float* __restrict__ W_ih, const float* __restrict__ W_hh,
                            const float* __restrict__ b_ih, const float* __restrict__ b_hh,
                            const float* __restrict__ W_out,
                            unsigned short* __restrict__ wsW, float* __restrict__ ws_beff) {
  int id = blockIdx.x * blockDim.x + threadIdx.x;
  if (id < 16384) {                       // W_eff fragments (16 ntiles, 2 ksteps)
    int j = id & 7, l = (id >> 3) & 63, nt = (id >> 9) & 15, ks = id >> 13;
    int n = nt * 16 + (l & 15);
    int k = ks * 32 + (l >> 4) * 8 + j;
    float s = 0.f;
    #pragma unroll 8
    for (int h = 0; h < 64; ++h) s = fmaf(W_ih[n * 64 + h], W_in[h * 64 + k], s);
    wsW[id] = f2bf(s);
  } else if (id < 32768) {                // W_hh fragments
    int e = id - 16384;
    int j = e & 7, l = (e >> 3) & 63, nt = (e >> 9) & 15, ks = e >> 13;
    int n = nt * 16 + (l & 15);
    int k = ks * 32 + (l >> 4) * 8 + j;
    wsW[id] = f2bf(W_hh[n * 64 + k]);
  } else if (id < 33792) {                // W_out fragments (1 ntile, 2 ksteps)
    int e = id - 32768;
    int j = e & 7, l = (e >> 3) & 63, ks = e >> 9;
    int n = l & 15;
    int k = ks * 32 + (l >> 4) * 8 + j;
    wsW[id] = f2bf(W_out[n * 64 + k]);
  } else if (id < 34048) {                // b_eff
    int n = id - 33792;
    float s = b_ih[n] + b_hh[n];
    #pragma unroll 8
    for (int h = 0; h < 64; ++h) s = fmaf(W_ih[n * 64 + h], b_in[h], s);
    ws_beff[n] = s;
  }
}

__device__ __forceinline__ short8 pack8(float4 lo, float4 hi) {
  short8 r;
  r[0] = (short)f2bf(lo.x); r[1] = (short)f2bf(lo.y);
  r[2] = (short)f2bf(lo.z); r[3] = (short)f2bf(lo.w);
  r[4] = (short)f2bf(hi.x); r[5] = (short)f2bf(hi.y);
  r[6] = (short)f2bf(hi.z); r[7] = (short)f2bf(hi.w);
  return r;
}

__global__ __launch_bounds__(BLOCK, 4) void lstm_main(
    const float* __restrict__ obs, const float* __restrict__ h0,
    const float* __restrict__ c0, const float* __restrict__ b_out,
    const unsigned short* __restrict__ wsW, const float* __restrict__ ws_beff,
    float* __restrict__ out) {
  // LDS: weight fragments 67584 B + beff 1 KB = 68608 B -> 2 blocks/CU.
  // hfrag (per-wave 2 KB transpose buffer) is UNIONED into the wE region,
  // which is dead after the gate MFMA loop (barrier in between).
  __shared__ __attribute__((aligned(16))) unsigned short wfrag[33792];
  __shared__ float beff_s[256];

  const int tid = threadIdx.x;
  const int wv = tid >> 6;
  const int lane = tid & 63;
  const int l16 = lane & 15;
  const int q = lane >> 4;                 // 0..3
  const size_t rowbase = (size_t)blockIdx.x * TILE + (size_t)wv * 16;

  // ---- issue A-operand global loads EARLY (before staging) ----
  const float* po = obs + (rowbase + l16) * 64 + q * 8;
  const float* ph = h0 + (rowbase + l16) * 64 + q * 8;
  float4 ro0 = *(const float4*)(po);
  float4 ro1 = *(const float4*)(po + 4);
  float4 ro2 = *(const float4*)(po + 32);
  float4 ro3 = *(const float4*)(po + 36);
  float4 rh0 = *(const float4*)(ph);
  float4 rh1 = *(const float4*)(ph + 4);
  float4 rh2 = *(const float4*)(ph + 32);
  float4 rh3 = *(const float4*)(ph + 36);

  // ---- stage packed weights ws -> LDS (uint4 = 8 bf16): 4224 chunks ----
  for (int i = tid; i < 4224; i += BLOCK)
    ((uint4*)wfrag)[i] = ((const uint4*)wsW)[i];
  if (tid < 256) beff_s[tid] = ws_beff[tid];
  __syncthreads();

  short8 aObs[2], aH[2];
  aObs[0] = pack8(ro0, ro1); aObs[1] = pack8(ro2, ro3);
  aH[0] = pack8(rh0, rh1);  aH[1] = pack8(rh2, rh3);

  // gates = obs@W_eff^T + h@W_hh^T + b_eff ; acc[t] covers cols t*16..t*16+15
  f32x4 acc[16];
  #pragma unroll
  for (int t = 0; t < 16; ++t) {
    float b = beff_s[t * 16 + l16];
    acc[t] = (f32x4){b, b, b, b};
  }
  const short8* wE = (const short8*)wfrag;            // [2][16][64]
  const short8* wH = (const short8*)(wfrag + 16384);  // [2][16][64]
  const short8* wO = (const short8*)(wfrag + 32768);  // [2][64]
  #pragma unroll
  for (int ks = 0; ks < 2; ++ks) {
    #pragma unroll
    for (int t = 0; t < 16; ++t) {
      acc[t] = __builtin_amdgcn_mfma_f32_16x16x32_bf16(aObs[ks], wE[(ks * 16 + t) * 64 + lane], acc[t], 0, 0, 0);
      acc[t] = __builtin_amdgcn_mfma_f32_16x16x32_bf16(aH[ks],  wH[(ks * 16 + t) * 64 + lane], acc[t], 0, 0, 0);
    }
  }

  // all waves done reading wE/wH -> safe to reuse wE region as hfrag
  __syncthreads();
  unsigned short* hbuf = wfrag + wv * 1024;   // per-wave [2][64][8]

  // elementwise LSTM cell; D layout: lane holds row 4*q+r, col t*16+l16
  float* out_act = out;
  float* out_h = out + (size_t)BT * 16;
  float* out_c = out + (size_t)BT * 16 + (size_t)BT * 64;

  #pragma unroll
  for (int t = 0; t < 4; ++t) {
    #pragma unroll
    for (int r = 0; r < 4; ++r) {
      float iv = sigm(acc[t][r]);
      float fv = sigm(acc[t + 4][r]);
      float gv = tanh_(acc[t + 8][r]);
      float ov = sigm(acc[t + 12][r]);
      size_t m = rowbase + (size_t)(4 * q + r);
      int n = t * 16 + l16;
      float cold = c0[m * 64 + n];
      float cnew = fmaf(fv, cold, iv * gv);
      float hnew = ov * tanh_(cnew);
      out_c[m * 64 + n] = cnew;
      out_h[m * 64 + n] = hnew;
      // scatter h_new into A-fragment layout for the W_out MFMA
      int ks = n >> 5;
      int lp = (4 * q + r) + 16 * ((n & 31) >> 3);
      int j = n & 7;
      hbuf[ks * 512 + lp * 8 + j] = f2bf(hnew);
    }
  }
  // hbuf is per-wave: same-wave ds_write -> ds_read needs no barrier

  // action = tanh(h_new @ W_out^T + b_out); ACTION range [-1,1] => identity map
  float bo = b_out[l16];
  f32x4 accA = (f32x4){bo, bo, bo, bo};
  short8 a0 = *(const short8*)(hbuf + lane * 8);
  short8 a1 = *(const short8*)(hbuf + 512 + lane * 8);
  accA = __builtin_amdgcn_mfma_f32_16x16x32_bf16(a0, wO[lane], accA, 0, 0, 0);
  accA = __builtin_amdgcn_mfma_f32_16x16x32_bf16(a1, wO[64 + lane], accA, 0, 0, 0);
  #pragma unroll
  for (int r = 0; r < 4; ++r) {
    size_t m = rowbase + (size_t)(4 * q + r);
    out_act[m * 16 + l16] = tanh_(accA[r]);
  }
}

extern "C" void kernel_launch(void* const* d_in, const int* in_sizes, int n_in,
                              void* d_out, int out_size, void* d_ws, size_t ws_size,
                              hipStream_t stream) {
  const float* obs  = (const float*)d_in[0];
  const float* h0   = (const float*)d_in[1];
  const float* c0   = (const float*)d_in[2];
  const float* W_in = (const float*)d_in[3];
  const float* b_in = (const float*)d_in[4];
  const float* W_ih = (const float*)d_in[5];
  const float* W_hh = (const float*)d_in[6];
  const float* b_ih = (const float*)d_in[7];
  const float* b_hh = (const float*)d_in[8];
  const float* W_out = (const float*)d_in[9];
  const float* b_out = (const float*)d_in[10];

  unsigned short* wsW = (unsigned short*)d_ws;
  float* ws_beff = (float*)((char*)d_ws + 67584);

  prep_kernel<<<133, 256, 0, stream>>>(W_in, b_in, W_ih, W_hh, b_ih, b_hh, W_out, wsW, ws_beff);
  lstm_main<<<BT / TILE, BLOCK, 0, stream>>>(obs, h0, c0, b_out, wsW, ws_beff, (float*)d_out);
}